// Round 3
// baseline (352.410 us; speedup 1.0000x reference)
//
#include <hip/hip_runtime.h>
#include <hip/hip_bf16.h>
#include <stdint.h>

typedef __bf16 bf16;
typedef __attribute__((ext_vector_type(8))) __bf16 bf16x8;
typedef __attribute__((ext_vector_type(4))) float f32x4;

#define KREAL 784
#define KPAD  800

// ---------------------------------------------------------------------------
// Prep: fold 3x3 VALID cross-correlation into w1.
// W1t[n][k] = sum_{di,dj} w_conv[di,dj] * w1[(r-di)*26 + (c-dj)][n],  k=(r,c)
// Stored TRANSPOSED (n-major, k contiguous, padded to 800) as bf16.
// ---------------------------------------------------------------------------
__global__ __launch_bounds__(256) void prep_w1t(const float* __restrict__ w_conv,
                                                const float* __restrict__ w1,
                                                bf16* __restrict__ W1t) {
    const int k = blockIdx.x;    // 0..799
    const int n = threadIdx.x;   // 0..255
    float s = 0.0f;
    if (k < KREAL) {
        const int r = k / 28, c = k % 28;
        #pragma unroll
        for (int di = 0; di < 3; ++di) {
            const int i = r - di;
            if (i < 0 || i >= 26) continue;
            #pragma unroll
            for (int dj = 0; dj < 3; ++dj) {
                const int j = c - dj;
                if (j < 0 || j >= 26) continue;
                s += w_conv[di * 3 + dj] * w1[(i * 26 + j) * 256 + n];
            }
        }
    }
    W1t[n * KPAD + k] = (bf16)s;   // pad region k>=784 gets 0
}

// ---------------------------------------------------------------------------
// Fused: out = relu(x @ W1' + b1) @ w2 + b2
// M=128/block, N=256 (full), BK=32. NO barriers in the K-loop:
//   A: global -> regs (the HBM stream, per-lane private)
//   B: global -> regs (400 KB total, L2/L1-resident, read-shared by all
//      blocks; 16 x 16B loads/lane/iter). Same bytes the old LDS path read,
//      so the verified MFMA mapping carries over.
// Epilogue: 256->10 on fp32 VALU with a 16-lane shfl_xor butterfly.
// ---------------------------------------------------------------------------
__global__ __launch_bounds__(256, 2) void fused_mlp(
    const float* __restrict__ x,    // (65536, 784)
    const bf16*  __restrict__ W1t,  // (256, 800) bf16
    const float* __restrict__ b1,   // (256)
    const float* __restrict__ w2,   // (256, 10)
    const float* __restrict__ b2,   // (10)
    float* __restrict__ out)        // (65536, 10)
{
    __shared__ float w2s[256][10];  // 10 KB
    __shared__ float b1s[256];
    __shared__ float b2s[10];

    const int t    = threadIdx.x;
    const int wave = t >> 6;
    const int lane = t & 63;
    const int c    = lane & 15;   // MFMA col / A-row within 16-tile
    const int q    = lane >> 4;   // MFMA quad (k-chunk selector)

    const int row0 = blockIdx.x * 128;

    // one-time stage of epilogue constants (barrier AFTER the K-loop)
    for (int i = t; i < 2560; i += 256) ((float*)w2s)[i] = w2[i];
    b1s[t] = b1[t];
    if (t < 10) b2s[t] = b2[t];

    // A: lane (c,q) owns rows (wave*32 + c) and (+16), k-chunk q*8..q*8+7
    const float* arow0 = x + (size_t)(row0 + wave * 32 + c) * KREAL + q * 8;
    const float* arow1 = arow0 + (size_t)16 * KREAL;
    // B: lane (c,q) reads W1t[nt*16 + c][k0 + q*8 .. +7] for nt=0..15
    const bf16* bbase = W1t + (size_t)c * KPAD + q * 8;

    f32x4 acc[2][16];
    #pragma unroll
    for (int mt = 0; mt < 2; ++mt)
        #pragma unroll
        for (int nt = 0; nt < 16; ++nt)
            acc[mt][nt] = (f32x4){0.f, 0.f, 0.f, 0.f};

    #pragma unroll 1
    for (int k0 = 0; k0 < KPAD; k0 += 32) {
        // ---- A first (HBM misses, longest latency) ----
        float4 f0a, f0b, f1a, f1b;
        if (k0 + q * 8 < KREAL) {   // 784 % 8 == 0: chunk fully in or out
            const float* p0 = arow0 + k0;
            const float* p1 = arow1 + k0;
            f0a = *(const float4*)p0; f0b = *(const float4*)(p0 + 4);
            f1a = *(const float4*)p1; f1b = *(const float4*)(p1 + 4);
        } else {
            f0a = f0b = f1a = f1b = (float4){0.f, 0.f, 0.f, 0.f};
        }

        // ---- B: 16 x 16B from L1/L2 ----
        bf16x8 bv[16];
        #pragma unroll
        for (int nt = 0; nt < 16; ++nt)
            bv[nt] = *(const bf16x8*)(bbase + (size_t)nt * 16 * KPAD + k0);

        // ---- convert A to bf16 ----
        bf16x8 a0, a1;
        a0[0] = (bf16)f0a.x; a0[1] = (bf16)f0a.y; a0[2] = (bf16)f0a.z; a0[3] = (bf16)f0a.w;
        a0[4] = (bf16)f0b.x; a0[5] = (bf16)f0b.y; a0[6] = (bf16)f0b.z; a0[7] = (bf16)f0b.w;
        a1[0] = (bf16)f1a.x; a1[1] = (bf16)f1a.y; a1[2] = (bf16)f1a.z; a1[3] = (bf16)f1a.w;
        a1[4] = (bf16)f1b.x; a1[5] = (bf16)f1b.y; a1[6] = (bf16)f1b.z; a1[7] = (bf16)f1b.w;

        // ---- MFMA: A[m=c][k=q*8+j], B[k=q*8+j][n=nt*16+c] ----
        #pragma unroll
        for (int nt = 0; nt < 16; ++nt) {
            acc[0][nt] = __builtin_amdgcn_mfma_f32_16x16x32_bf16(a0, bv[nt], acc[0][nt], 0, 0, 0);
            acc[1][nt] = __builtin_amdgcn_mfma_f32_16x16x32_bf16(a1, bv[nt], acc[1][nt], 0, 0, 0);
        }
    }

    __syncthreads();  // w2s/b1s/b2s visibility for the epilogue

    // ---- epilogue: h = relu(acc + b1); out = h @ w2 + b2 ----
    // C/D layout: col = lane&15 (= n within tile), row = q*4 + reg
    float bl[16];
    #pragma unroll
    for (int nt = 0; nt < 16; ++nt) bl[nt] = b1s[nt * 16 + c];

    #pragma unroll
    for (int mt = 0; mt < 2; ++mt)
        #pragma unroll
        for (int nt = 0; nt < 16; ++nt)
            #pragma unroll
            for (int r = 0; r < 4; ++r) {
                float v = acc[mt][nt][r] + bl[nt];
                acc[mt][nt][r] = v > 0.f ? v : 0.f;
            }

    #pragma unroll 1
    for (int j = 0; j < 10; ++j) {
        float wj[16];
        #pragma unroll
        for (int nt = 0; nt < 16; ++nt) wj[nt] = w2s[nt * 16 + c][j];
        const float b2j = b2s[j];
        #pragma unroll
        for (int mt = 0; mt < 2; ++mt)
            #pragma unroll
            for (int r = 0; r < 4; ++r) {
                float s = 0.f;
                #pragma unroll
                for (int nt = 0; nt < 16; ++nt) s += acc[mt][nt][r] * wj[nt];
                s += __shfl_xor(s, 1, 64);
                s += __shfl_xor(s, 2, 64);
                s += __shfl_xor(s, 4, 64);
                s += __shfl_xor(s, 8, 64);
                if (c == j) {
                    const int row = row0 + wave * 32 + mt * 16 + q * 4 + r;
                    out[(size_t)row * 10 + j] = s + b2j;
                }
            }
    }
}

extern "C" void kernel_launch(void* const* d_in, const int* in_sizes, int n_in,
                              void* d_out, int out_size, void* d_ws, size_t ws_size,
                              hipStream_t stream) {
    const float* x  = (const float*)d_in[0];
    const float* wc = (const float*)d_in[1];
    const float* w1 = (const float*)d_in[2];
    const float* b1 = (const float*)d_in[3];
    const float* w2 = (const float*)d_in[4];
    const float* b2 = (const float*)d_in[5];
    float* out = (float*)d_out;
    bf16* W1t = (bf16*)d_ws;  // 256*800*2 = 400 KB scratch

    prep_w1t<<<dim3(KPAD), dim3(256), 0, stream>>>(wc, w1, W1t);
    fused_mlp<<<dim3(65536 / 128), dim3(256), 0, stream>>>(x, W1t, b1, w2, b2, out);
}

// Round 4
// 316.953 us; speedup vs baseline: 1.1119x; 1.1119x over previous
//
#include <hip/hip_runtime.h>
#include <hip/hip_bf16.h>
#include <stdint.h>

typedef __bf16 bf16;
typedef __attribute__((ext_vector_type(8))) __bf16 bf16x8;
typedef __attribute__((ext_vector_type(4))) float f32x4;

#define KREAL 784
#define NTILES 25            // 25 k-tiles of 32
#define TROW   40            // row length in elements within a k-tile (32 + 8 pad)
#define TILE_ELEMS (256 * TROW)   // 10240 elements = 20 KB per k-tile

#define GLOBAL_AS __attribute__((address_space(1)))
#define LDS_AS    __attribute__((address_space(3)))

// ---------------------------------------------------------------------------
// Prep: fold 3x3 VALID cross-correlation into w1, emit k-tiled, row-padded:
//   W[tile][n][kk]  kk in [0,40), value for k = tile*32+kk when kk<32 & k<784,
//   else 0. The 80 B row stride makes the GEMM's ds_read_b128 2-way-only on
//   banks (free), and the pad lives in GLOBAL memory so global_load_lds's
//   (wave-uniform base + lane*16) rule still sees one contiguous region.
// ---------------------------------------------------------------------------
__global__ __launch_bounds__(256) void prep_w1tt(const float* __restrict__ w_conv,
                                                 const float* __restrict__ w1,
                                                 bf16* __restrict__ W) {
    const int tile = blockIdx.x / TROW;
    const int kk   = blockIdx.x % TROW;
    const int n    = threadIdx.x;
    const int k    = tile * 32 + kk;
    float s = 0.0f;
    if (kk < 32 && k < KREAL) {
        const int r = k / 28, c = k % 28;
        #pragma unroll
        for (int di = 0; di < 3; ++di) {
            const int i = r - di;
            if (i < 0 || i >= 26) continue;
            #pragma unroll
            for (int dj = 0; dj < 3; ++dj) {
                const int j = c - dj;
                if (j < 0 || j >= 26) continue;
                s += w_conv[di * 3 + dj] * w1[(i * 26 + j) * 256 + n];
            }
        }
    }
    W[(size_t)tile * TILE_ELEMS + n * TROW + kk] = (bf16)s;
}

// ---------------------------------------------------------------------------
// Fused: out = relu(x @ W1' + b1) @ w2 + b2
// M=128/block, N=256 (full), BK=32, ONE barrier per K-iter:
//   A: global -> float regs (prefetched one iter ahead, cvt after MFMAs)
//   B: global_load_lds DMA into double-buffered Bs (20 KB/tile), issued one
//      iter ahead; barrier drain therefore only forces next-iter data.
// Epilogue: 256->10 on fp32 VALU with a 16-lane shfl_xor butterfly.
// ---------------------------------------------------------------------------
__global__ __launch_bounds__(256, 2) void fused_mlp(
    const float* __restrict__ x,    // (65536, 784)
    const bf16*  __restrict__ W,    // k-tiled padded W1' (25*10240 bf16)
    const float* __restrict__ b1,   // (256)
    const float* __restrict__ w2,   // (256, 10)
    const float* __restrict__ b2,   // (10)
    float* __restrict__ out)        // (65536, 10)
{
    __shared__ bf16  Bs[2][TILE_ELEMS];  // 2 x 20 KB
    __shared__ float w2s[256][10];       // 10 KB
    __shared__ float b1s[256];
    __shared__ float b2s[10];

    const int t    = threadIdx.x;
    const int wave = t >> 6;
    const int lane = t & 63;
    const int c    = lane & 15;   // MFMA col / A-row within 16-tile
    const int q    = lane >> 4;   // MFMA quad (k-chunk selector)

    const int row0 = blockIdx.x * 128;

    // one-time stage of epilogue constants (pre-loop barrier publishes them)
    for (int i = t; i < 2560; i += 256) ((float*)w2s)[i] = w2[i];
    b1s[t] = b1[t];
    if (t < 10) b2s[t] = b2[t];

    // A: lane (c,q) owns rows (wave*32 + c) and (+16), k-chunk q*8..q*8+7
    const float* arow0 = x + (size_t)(row0 + wave * 32 + c) * KREAL + q * 8;
    const float* arow1 = arow0 + (size_t)16 * KREAL;
    // B DMA: wave w, instr j stages elements [(w*5+j)*512, +512) of the tile
    const bf16* bsrc = W + (size_t)(wave * 5) * 512 + lane * 8;

    f32x4 acc[2][16];
    #pragma unroll
    for (int mt = 0; mt < 2; ++mt)
        #pragma unroll
        for (int nt = 0; nt < 16; ++nt)
            acc[mt][nt] = (f32x4){0.f, 0.f, 0.f, 0.f};

    // ---- prologue: DMA tile 0, load+cvt A(0) ----
    #pragma unroll
    for (int j = 0; j < 5; ++j) {
        __builtin_amdgcn_global_load_lds(
            (const GLOBAL_AS void*)(bsrc + j * 512),
            (LDS_AS void*)((char*)&Bs[0][0] + (wave * 5 + j) * 1024), 16, 0, 0);
    }
    float4 f0a = *(const float4*)arow0, f0b = *(const float4*)(arow0 + 4);
    float4 f1a = *(const float4*)arow1, f1b = *(const float4*)(arow1 + 4);
    bf16x8 a0, a1;
    a0[0] = (bf16)f0a.x; a0[1] = (bf16)f0a.y; a0[2] = (bf16)f0a.z; a0[3] = (bf16)f0a.w;
    a0[4] = (bf16)f0b.x; a0[5] = (bf16)f0b.y; a0[6] = (bf16)f0b.z; a0[7] = (bf16)f0b.w;
    a1[0] = (bf16)f1a.x; a1[1] = (bf16)f1a.y; a1[2] = (bf16)f1a.z; a1[3] = (bf16)f1a.w;
    a1[4] = (bf16)f1b.x; a1[5] = (bf16)f1b.y; a1[6] = (bf16)f1b.z; a1[7] = (bf16)f1b.w;
    __syncthreads();   // tile 0 resident; w2s/b1s/b2s published

    #pragma unroll 1
    for (int it = 0; it < NTILES; ++it) {
        const int cur = it & 1;
        const bool more = (it + 1) < NTILES;

        // ---- prefetch next iter: B-DMA + A float loads (issued first) ----
        if (more) {
            const bf16* bs = bsrc + (size_t)(it + 1) * TILE_ELEMS;
            char* bd = (char*)&Bs[cur ^ 1][0] + wave * 5 * 1024;
            #pragma unroll
            for (int j = 0; j < 5; ++j) {
                __builtin_amdgcn_global_load_lds(
                    (const GLOBAL_AS void*)(bs + j * 512),
                    (LDS_AS void*)(bd + j * 1024), 16, 0, 0);
            }
            const int kn = (it + 1) * 32;
            if (kn + q * 8 < KREAL) {   // zero-guard (784 % 8 == 0)
                const float* p0 = arow0 + kn;
                const float* p1 = arow1 + kn;
                f0a = *(const float4*)p0; f0b = *(const float4*)(p0 + 4);
                f1a = *(const float4*)p1; f1b = *(const float4*)(p1 + 4);
            } else {
                f0a = f0b = f1a = f1b = (float4){0.f, 0.f, 0.f, 0.f};
            }
        }

        // ---- MFMA on current tile: A[m=c][k=q*8+j], B row stride 80 B ----
        #pragma unroll
        for (int nt = 0; nt < 16; ++nt) {
            bf16x8 b = *(const bf16x8*)&Bs[cur][(nt * 16 + c) * TROW + q * 8];
            acc[0][nt] = __builtin_amdgcn_mfma_f32_16x16x32_bf16(a0, b, acc[0][nt], 0, 0, 0);
            acc[1][nt] = __builtin_amdgcn_mfma_f32_16x16x32_bf16(a1, b, acc[1][nt], 0, 0, 0);
        }

        // ---- convert prefetched A (waits on A loads AFTER compute) ----
        if (more) {
            a0[0] = (bf16)f0a.x; a0[1] = (bf16)f0a.y; a0[2] = (bf16)f0a.z; a0[3] = (bf16)f0a.w;
            a0[4] = (bf16)f0b.x; a0[5] = (bf16)f0b.y; a0[6] = (bf16)f0b.z; a0[7] = (bf16)f0b.w;
            a1[0] = (bf16)f1a.x; a1[1] = (bf16)f1a.y; a1[2] = (bf16)f1a.z; a1[3] = (bf16)f1a.w;
            a1[4] = (bf16)f1b.x; a1[5] = (bf16)f1b.y; a1[6] = (bf16)f1b.z; a1[7] = (bf16)f1b.w;
        }

        __syncthreads();   // next tile resident; old buffer reads done
    }

    // ---- epilogue: h = relu(acc + b1); out = h @ w2 + b2 ----
    // C/D layout: col = lane&15 (= n within tile), row = q*4 + reg
    float bl[16];
    #pragma unroll
    for (int nt = 0; nt < 16; ++nt) bl[nt] = b1s[nt * 16 + c];

    #pragma unroll
    for (int mt = 0; mt < 2; ++mt)
        #pragma unroll
        for (int nt = 0; nt < 16; ++nt)
            #pragma unroll
            for (int r = 0; r < 4; ++r) {
                float v = acc[mt][nt][r] + bl[nt];
                acc[mt][nt][r] = v > 0.f ? v : 0.f;
            }

    #pragma unroll 1
    for (int j = 0; j < 10; ++j) {
        float wj[16];
        #pragma unroll
        for (int nt = 0; nt < 16; ++nt) wj[nt] = w2s[nt * 16 + c][j];
        const float b2j = b2s[j];
        #pragma unroll
        for (int mt = 0; mt < 2; ++mt)
            #pragma unroll
            for (int r = 0; r < 4; ++r) {
                float s = 0.f;
                #pragma unroll
                for (int nt = 0; nt < 16; ++nt) s += acc[mt][nt][r] * wj[nt];
                s += __shfl_xor(s, 1, 64);
                s += __shfl_xor(s, 2, 64);
                s += __shfl_xor(s, 4, 64);
                s += __shfl_xor(s, 8, 64);
                if (c == j) {
                    const int row = row0 + wave * 32 + mt * 16 + q * 4 + r;
                    out[(size_t)row * 10 + j] = s + b2j;
                }
            }
    }
}

extern "C" void kernel_launch(void* const* d_in, const int* in_sizes, int n_in,
                              void* d_out, int out_size, void* d_ws, size_t ws_size,
                              hipStream_t stream) {
    const float* x  = (const float*)d_in[0];
    const float* wc = (const float*)d_in[1];
    const float* w1 = (const float*)d_in[2];
    const float* b1 = (const float*)d_in[3];
    const float* w2 = (const float*)d_in[4];
    const float* b2 = (const float*)d_in[5];
    float* out = (float*)d_out;
    bf16* W = (bf16*)d_ws;  // 25 * 10240 * 2 B = 500 KB scratch

    prep_w1tt<<<dim3(NTILES * TROW), dim3(256), 0, stream>>>(wc, w1, W);
    fused_mlp<<<dim3(65536 / 128), dim3(256), 0, stream>>>(x, W, b1, w2, b2, out);
}